// Round 5
// baseline (70.804 us; speedup 1.0000x reference)
//
#include <hip/hip_runtime.h>
#include <hip/hip_bf16.h>

#define ACTIONS 64
#define EMB 32
#define DELTA 16
#define EPS 1e-5f

typedef float f32x4 __attribute__((ext_vector_type(4)));

// tanh(x) = 1 - 2/(1+exp(2x)); saturates correctly at +-1.
__device__ __forceinline__ float fast_tanhf(float x) {
    float e = __expf(2.0f * x);
    float r = __builtin_amdgcn_rcpf(1.0f + e);
    return 1.0f - 2.0f * r;
}

// ---------------- Kernel 1: per-column partial sums (float4) ----------------
__global__ void __launch_bounds__(256) bn_stats_kernel(const f32x4* __restrict__ x4,
                                                       float* __restrict__ partial,
                                                       int total4 /* n*64/4 */) {
    const int tid = threadIdx.x;
    f32x4 s = {0.f, 0.f, 0.f, 0.f};
    f32x4 q = {0.f, 0.f, 0.f, 0.f};
    const int stride = gridDim.x * 256;
    for (int i = blockIdx.x * 256 + tid; i < total4; i += stride) {
        f32x4 v = x4[i];
        s += v;
        q += v * v;
    }
    __shared__ f32x4 ssum[256];
    __shared__ f32x4 ssq[256];
    ssum[tid] = s;
    ssq[tid] = q;
    __syncthreads();
    if (tid < 16) {
        f32x4 a = ssum[tid];
        f32x4 b = ssq[tid];
        #pragma unroll
        for (int k = 1; k < 16; ++k) {
            a += ssum[tid + 16 * k];
            b += ssq[tid + 16 * k];
        }
        float* ps = partial + blockIdx.x * 128;
        #pragma unroll
        for (int j = 0; j < 4; ++j) {
            ps[4 * tid + j]      = a[j];
            ps[64 + 4 * tid + j] = b[j];
        }
    }
}

// ---------------- Kernel 2: fold partials -> scale/shift ----------------
__global__ void __launch_bounds__(64) bn_finalize_kernel(const float* __restrict__ partial,
                                                         const float* __restrict__ w,
                                                         const float* __restrict__ b,
                                                         float* __restrict__ scaleshift,
                                                         int nblocks, float inv_n) {
    const int c = threadIdx.x;  // 0..63
    float s = 0.0f, sq = 0.0f;
    for (int i = 0; i < nblocks; ++i) {
        s  += partial[i * 128 + c];
        sq += partial[i * 128 + 64 + c];
    }
    float mean = s * inv_n;
    float var  = fmaxf(sq * inv_n - mean * mean, 0.0f);
    float scale = rsqrtf(var + EPS) * w[c];
    scaleshift[c]      = scale;
    scaleshift[64 + c] = b[c] - mean * scale;
}

// ---------------- Kernel 3: main spline-embedding, LDS-staged table --------
// Block owns 8 columns x 128 rows. Sub-table (33 knots x 8 cols x 128 B =
// 33 KiB) staged to LDS once. Main loop: 4-deep software pipeline — 4 rows'
// x loaded up front, then 4 independent compute+store pipelines. PLAIN
// writeback stores (this round's experiment: nt flag suspected of breaking
// L2 write-coalescing; harness fill hits 6.7 TB/s with plain stores).
__global__ void __launch_bounds__(256) spline_lds_kernel(const float* __restrict__ x,
                                                         const f32x4* __restrict__ emb4,
                                                         const float* __restrict__ scaleshift,
                                                         f32x4* __restrict__ out4,
                                                         int rows_per_tile) {
    __shared__ f32x4 tab4[33 * 8 * 8];   // [knot k][ci][e4]
    const int tid     = threadIdx.x;
    const int colgrp  = blockIdx.x & 7;
    const int rowtile = blockIdx.x >> 3;
    const int c0      = colgrp * 8;

    // Stage sub-table: contiguous 1 KiB per wave per step. One-time.
    for (int u = tid; u < 33 * 64; u += 256) {
        const int k    = u >> 6;
        const int rest = u & 63;                 // ci*8 + e4
        tab4[u] = emb4[k * 512 + c0 * 8 + rest];
    }

    const int ci  = (tid >> 3) & 7;   // column within group
    const int e4  = tid & 7;          // which float4 of the 32-float emb row
    const int col = c0 + ci;
    const float scale = scaleshift[col];
    const float shift = scaleshift[64 + col];
    __syncthreads();

    const int row_off = tid >> 6;     // 0..3: each wave owns one x-row per step
    const int r_base  = rowtile * rows_per_tile + row_off;
    const int iters   = rows_per_tile >> 4;   // 4 rows per wave per body

    for (int it = 0; it < iters; ++it) {
        const int r = r_base + it * 16;
        // ---- batch loads: 4 independent x reads in flight ----
        float xv[4];
        #pragma unroll
        for (int j = 0; j < 4; ++j)
            xv[j] = x[(r + 4 * j) * ACTIONS + col];

        // ---- 4 independent pipelines ----
        #pragma unroll
        for (int j = 0; j < 4; ++j) {
            float t = fast_tanhf(fmaf(xv[j], scale, shift));
            t = fminf(fmaxf(t, -1.0f + 1e-5f), 1.0f - 1e-5f);

            const float td  = t * (float)DELTA;
            const float xlf = floorf(td);
            const float xhf = floorf(td + 1.0f);     // mirror reference
            const int kl = (int)xlf + DELTA;         // 0..31
            const int kh = (int)xhf + DELTA;         // 1..32
            const float wl = xhf - td;               // D*(xh - t)
            const float wh = td - xlf;               // D*(t - xl)

            const f32x4 bl = tab4[(kl * 8 + ci) * 8 + e4];
            const f32x4 bh = tab4[(kh * 8 + ci) * 8 + e4];
            f32x4 o = bh * wh + bl * wl;
            // contiguous across the wave's 64 lanes -> 1 KiB segment
            out4[((r + 4 * j) * ACTIONS + col) * 8 + e4] = o;
        }
    }
}

extern "C" void kernel_launch(void* const* d_in, const int* in_sizes, int n_in,
                              void* d_out, int out_size, void* d_ws, size_t ws_size,
                              hipStream_t stream) {
    const float* x    = (const float*)d_in[0];
    const float* bn_w = (const float*)d_in[1];
    const float* bn_b = (const float*)d_in[2];
    const float* emb  = (const float*)d_in[3];
    float* out        = (float*)d_out;

    const int n = in_sizes[0] / ACTIONS;   // 16384
    const int total = n * ACTIONS;

    float* partial    = (float*)d_ws;                 // 128 * 128 floats
    float* scaleshift = (float*)d_ws + 128 * 128;     // 128 floats

    const int STATS_BLOCKS = 128;
    bn_stats_kernel<<<STATS_BLOCKS, 256, 0, stream>>>((const f32x4*)x, partial, total / 4);
    bn_finalize_kernel<<<1, 64, 0, stream>>>(partial, bn_w, bn_b, scaleshift,
                                             STATS_BLOCKS, 1.0f / (float)n);

    // 8 col-groups x 128 row-tiles = 1024 blocks (4/CU, LDS-limited occupancy)
    const int ROWTILES = 128;
    const int rows_per_tile = n / ROWTILES;   // 128
    spline_lds_kernel<<<8 * ROWTILES, 256, 0, stream>>>(x, (const f32x4*)emb,
                                                        scaleshift, (f32x4*)out,
                                                        rows_per_tile);
}

// Round 6
// 35.529 us; speedup vs baseline: 1.9929x; 1.9929x over previous
//
#include <hip/hip_runtime.h>
#include <hip/hip_bf16.h>

#define ACTIONS 64
#define EMB 32
#define DELTA 16
#define EPS 1e-5f

typedef float f32x4 __attribute__((ext_vector_type(4)));

// tanh(x) = 1 - 2/(1+exp(2x)); saturates correctly at +-1.
__device__ __forceinline__ float fast_tanhf(float x) {
    float e = __expf(2.0f * x);
    float r = __builtin_amdgcn_rcpf(1.0f + e);
    return 1.0f - 2.0f * r;
}

// ---------------- Kernel 1: per-column partial sums (float4) ----------------
__global__ void __launch_bounds__(256) bn_stats_kernel(const f32x4* __restrict__ x4,
                                                       float* __restrict__ partial,
                                                       int total4 /* n*64/4 */) {
    const int tid = threadIdx.x;
    f32x4 s = {0.f, 0.f, 0.f, 0.f};
    f32x4 q = {0.f, 0.f, 0.f, 0.f};
    const int stride = gridDim.x * 256;
    for (int i = blockIdx.x * 256 + tid; i < total4; i += stride) {
        f32x4 v = x4[i];
        s += v;
        q += v * v;
    }
    __shared__ f32x4 ssum[256];
    __shared__ f32x4 ssq[256];
    ssum[tid] = s;
    ssq[tid] = q;
    __syncthreads();
    if (tid < 16) {
        f32x4 a = ssum[tid];
        f32x4 b = ssq[tid];
        #pragma unroll
        for (int k = 1; k < 16; ++k) {
            a += ssum[tid + 16 * k];
            b += ssq[tid + 16 * k];
        }
        float* ps = partial + blockIdx.x * 128;
        #pragma unroll
        for (int j = 0; j < 4; ++j) {
            ps[4 * tid + j]      = a[j];
            ps[64 + 4 * tid + j] = b[j];
        }
    }
}

// ---------------- Kernel 2: main spline-embedding -------------------------
// Block = 8 cols x 128 rows. Setup: stage 33-knot sub-table (33 KB) + the
// block's x-slice (4 KB) into LDS, and fold bn-finalize in (reduce the 64 KB
// partials for these 8 cols; L2-broadcast across blocks). Steady loop has
// ZERO global loads -> no vmcnt waits -> the nt-store stream never drains
// (theory: in-order vmcnt made every x-load wait drain all older stores).
__global__ void __launch_bounds__(256) spline_main_kernel(
        const f32x4* __restrict__ x4,
        const f32x4* __restrict__ emb4,
        const float* __restrict__ partial,
        const float* __restrict__ bn_w,
        const float* __restrict__ bn_b,
        f32x4* __restrict__ out4,
        float inv_n, int nstat) {
    __shared__ f32x4 tab4[33 * 64];     // [knot][ci][e4]  33 KB
    __shared__ f32x4 xs4[256];          // 128 rows x 8 cols  4 KB
    __shared__ float psum[2][8][8];     // [half][ci][chunk]

    const int tid     = threadIdx.x;
    const int colgrp  = blockIdx.x & 7;
    const int rowtile = blockIdx.x >> 3;
    const int c0      = colgrp * 8;
    const int r0      = rowtile * 128;

    // stage sub-table (contiguous 1 KiB per wave-step)
    for (int u = tid; u < 33 * 64; u += 256) {
        const int k = u >> 6, rest = u & 63;
        tab4[u] = emb4[k * 512 + c0 * 8 + rest];
    }
    // stage x slice: thread t -> local row t>>1, half t&1 (32B per row)
    xs4[tid] = x4[(r0 + (tid >> 1)) * 16 + (c0 >> 2) + (tid & 1)];

    // partial reduction for this block's 8 columns (fixed order -> determ.)
    if (tid < 128) {
        const int pci = tid & 7, half = (tid >> 3) & 1, chunk = tid >> 4;
        float s = 0.f;
        for (int k = 0; k < 16; ++k)
            s += partial[(chunk * 16 + k) * 128 + half * 64 + c0 + pci];
        psum[half][pci][chunk] = s;
    }
    __syncthreads();

    const int ci      = (tid >> 3) & 7;   // column within group
    const int e4      = tid & 7;          // float4 within emb row
    const int row_off = tid >> 6;         // wave id 0..3
    float scale, shift;
    {
        float s = 0.f, q = 0.f;
        #pragma unroll
        for (int k = 0; k < 8; ++k) { s += psum[0][ci][k]; q += psum[1][ci][k]; }
        const float mean = s * inv_n;
        const float var  = fmaxf(q * inv_n - mean * mean, 0.0f);
        scale = rsqrtf(var + EPS) * bn_w[c0 + ci];
        shift = bn_b[c0 + ci] - mean * scale;
    }

    const float* xs = (const float*)xs4;
    #pragma unroll 4
    for (int it = 0; it < 32; ++it) {
        const int rl = it * 4 + row_off;           // local row
        const float xv = xs[rl * 8 + ci];          // LDS broadcast read

        float t = fast_tanhf(fmaf(xv, scale, shift));
        t = fminf(fmaxf(t, -1.0f + 1e-5f), 1.0f - 1e-5f);

        const float td  = t * (float)DELTA;
        const float xlf = floorf(td);
        const float xhf = floorf(td + 1.0f);       // mirror reference
        const int kl = (int)xlf + DELTA;           // 0..31
        const int kh = (int)xhf + DELTA;           // 1..32
        const float wl = xhf - td;
        const float wh = td - xlf;

        const f32x4 bl = tab4[kl * 64 + ci * 8 + e4];
        const f32x4 bh = tab4[kh * 64 + ci * 8 + e4];
        f32x4 o = bh * wh + bl * wl;
        // contiguous across the wave's 64 lanes -> 1 KiB segment
        __builtin_nontemporal_store(o, &out4[((r0 + rl) * ACTIONS + c0 + ci) * 8 + e4]);
    }
    (void)nstat;
}

extern "C" void kernel_launch(void* const* d_in, const int* in_sizes, int n_in,
                              void* d_out, int out_size, void* d_ws, size_t ws_size,
                              hipStream_t stream) {
    const float* x    = (const float*)d_in[0];
    const float* bn_w = (const float*)d_in[1];
    const float* bn_b = (const float*)d_in[2];
    const float* emb  = (const float*)d_in[3];
    float* out        = (float*)d_out;

    const int n = in_sizes[0] / ACTIONS;   // 16384
    const int total = n * ACTIONS;

    float* partial = (float*)d_ws;         // 128 * 128 floats

    const int STATS_BLOCKS = 128;
    bn_stats_kernel<<<STATS_BLOCKS, 256, 0, stream>>>((const f32x4*)x, partial, total / 4);

    // 8 col-groups x (n/128) row-tiles; 4 blocks/CU (38.4 KB LDS each)
    const int blocks = 8 * (n / 128);      // 1024
    spline_main_kernel<<<blocks, 256, 0, stream>>>((const f32x4*)x, (const f32x4*)emb,
                                                   partial, bn_w, bn_b, (f32x4*)out,
                                                   1.0f / (float)n, STATS_BLOCKS);
}